// Round 2
// baseline (475.305 us; speedup 1.0000x reference)
//
#include <hip/hip_runtime.h>
#include <hip/hip_bf16.h>
#include <cstring>

// Problem constants: B=2, X=96, Y=96, Z=64, C=32, K=16, LOG_PROB_SCALE=200
#define NVOX (2 * 96 * 96 * 64)
#define K_TOT 16
#define N_TILES (NVOX / 128)   // 9216 tiles of 128 voxels; 1 tile per wave-iter
#define N_WAVES 3072           // persistent: 768 blocks x 4 waves; 3 tiles/wave
#define N_BLOCKS 768

typedef __attribute__((ext_vector_type(8)))  short short8;   // 8 bf16 (A/B frag)
typedef __attribute__((ext_vector_type(16))) float f32x16;   // C/D frag
typedef __attribute__((ext_vector_type(2)))  float f32x2;
typedef __attribute__((ext_vector_type(2)))  unsigned int uint2v;

// ws layout:
//   bytes [0, 32768): A-frags bf16, ushort idx ((kc*2 + half)*64 + lane)*8 + j
//       = Linv[kc][m = lane&31][c = half*16 + (lane>>5)*8 + j]
//   floats [8192, 8704): uf[kc*32 + (lane>>5)*16 + reg] = -u_kc[(reg&3)+8*(reg>>2)+4*(lane>>5)]
//   floats [8704, 8736): pairs (h2[kc], w[kc]); h2 = log2e*(const - logdet)/200
#define WS_UF 8192
#define WS_HW 8704
#define WS_FLOATS 8736   // 34944 bytes

static __device__ __forceinline__ unsigned short f2b(float f) {
    __hip_bfloat16 h = __float2bfloat16(f);
    unsigned short u;
    __builtin_memcpy(&u, &h, 2);
    return u;
}

// Pack two f32 into a dword of two bf16 (round-half-up): 2x v_add_u32 + v_perm_b32.
static __device__ __forceinline__ int pack2_bf16(float f0, float f1) {
    unsigned a, b;
    __builtin_memcpy(&a, &f0, 4);
    __builtin_memcpy(&b, &f1, 4);
    return (int)__builtin_amdgcn_perm(b + 0x8000u, a + 0x8000u, 0x07060302u);
}

static __device__ __forceinline__ short8 cvt8(float4 lo, float4 hi) {
    int p0 = pack2_bf16(lo.x, lo.y);
    int p1 = pack2_bf16(lo.z, lo.w);
    int p2 = pack2_bf16(hi.x, hi.y);
    int p3 = pack2_bf16(hi.z, hi.w);
    int v[4] = {p0, p1, p2, p3};
    short8 r;
    __builtin_memcpy(&r, v, 16);
    return r;
}

// readfirstlane for float (value is wave-uniform; pins it into an SGPR)
static __device__ __forceinline__ float rfl(float x) {
    int i;
    __builtin_memcpy(&i, &x, 4);
    i = __builtin_amdgcn_readfirstlane(i);
    float r;
    __builtin_memcpy(&r, &i, 4);
    return r;
}

// Sum p across the two 32-lane halves: returns p[lane] + p[lane^32] in every
// lane. Uses the permlane32_swap BUILTIN (compiler models the two-output
// semantics; round-1 inline-asm version with aliased tied "+v" operands could
// legally collapse to a single-register self-swap -> wrong sum).
static __device__ __forceinline__ float cross_half_sum(float p) {
#if __has_builtin(__builtin_amdgcn_permlane32_swap)
    unsigned pu;
    __builtin_memcpy(&pu, &p, 4);
    uint2v r = __builtin_amdgcn_permlane32_swap(pu, pu, false, false);
    unsigned a = r.x, b = r.y;
    float fa, fb;
    __builtin_memcpy(&fa, &a, 4);
    __builtin_memcpy(&fb, &b, 4);
    return fa + fb;   // {lo,lo} + {hi,hi} in each lane = p + p[lane^32]
#else
    return p + __shfl_xor(p, 32);
#endif
}

__global__ void gmm_prep_kernel(const float* __restrict__ wb, const float* __restrict__ mb,
                                const float* __restrict__ Lb, const float* __restrict__ wf,
                                const float* __restrict__ mf, const float* __restrict__ Lf,
                                float* __restrict__ ws) {
    int k   = blockIdx.x;   // component
    int tid = threadIdx.x;  // 64 threads

    __shared__ float Lsh[1024];   // L_k row-major
    __shared__ float Lish[1024];  // Linv_k row-major (upper tri = 0)
    __shared__ float ush[32];     // u = Linv * mu

    const float* L  = (k < 8) ? (Lb + k * 1024) : (Lf + (k - 8) * 1024);
    const float* mu = (k < 8) ? (mb + k * 32)   : (mf + (k - 8) * 32);

    for (int i = tid; i < 1024; i += 64) Lsh[i] = L[i];
    __syncthreads();

    if (tid < 32) {
        int j = tid;  // solve column j: L * col = e_j
        float col[32];
#pragma unroll
        for (int i = 0; i < 32; ++i) {
            float s = (i == j) ? 1.0f : 0.0f;
#pragma unroll
            for (int m = 0; m < i; ++m) s = fmaf(-Lsh[i * 32 + m], col[m], s);
            float val = s / Lsh[i * 32 + i];
            col[i] = (i >= j) ? val : 0.0f;
        }
#pragma unroll
        for (int i = 0; i < 32; ++i) Lish[i * 32 + j] = col[i];
    }
    __syncthreads();
    if (tid < 32) {
        int d = tid;
        float s = 0.0f;
        for (int c = 0; c <= d; ++c) s = fmaf(Lish[d * 32 + c], mu[c], s);
        ush[d] = s;
    }
    __syncthreads();

    // A-fragments in MFMA 32x32x16 operand order, bf16 (RNE; prep is cold).
    unsigned short* wsA = (unsigned short*)ws;
    int m  = tid & 31;   // outdim row
    int kq = tid >> 5;   // k-half-of-8 within the MFMA's K=16
#pragma unroll
    for (int hf = 0; hf < 2; ++hf) {  // channel halves 0..15 / 16..31
        unsigned short* dst = wsA + (size_t)(((k * 2 + hf) * 64 + tid) * 8);
#pragma unroll
        for (int j = 0; j < 8; ++j)
            dst[j] = f2b(Lish[m * 32 + hf * 16 + kq * 8 + j]);
    }
    // -u in C/D fragment order
    if (tid < 32) {
        int h = tid >> 4, r = tid & 15;
        ws[WS_UF + k * 32 + tid] = -ush[(r & 3) + 8 * (r >> 2) + 4 * h];
    }
    if (tid == 0) {
        float ld = 0.0f;
        for (int i = 0; i < 32; ++i) ld += logf(Lsh[i * 32 + i]);
        const float cconst = -0.5f * 32.0f * 1.8378770664093453f;  // -C/2*log(2pi)
        const float log2e  = 1.4426950408889634f;
        ws[WS_HW + k * 2]     = (cconst - ld) * (1.0f / 200.0f) * log2e;
        ws[WS_HW + k * 2 + 1] = (k < 8) ? wb[k] : wf[k - 8];
    }
}

// Persistent kernel: 768 blocks x 4 waves = 3072 waves, 3 tiles per wave.
// Cross-tile software pipeline: tile t+1's 16 raw float4 loads are issued
// between kc=7 and kc=8 of tile t's k-loop (~1000 cyc of MFMA/VALU hide the
// HBM latency); cvt-to-bf16 runs after the k-loop when the data has landed.
// Live-set peak ~160 VGPR (raw 64 + B 32 + Cu 16 + d + misc) under the
// __launch_bounds__(256,3) 168-reg budget -> 12 waves/CU as before.
__global__ __launch_bounds__(256, 3) void gmm_density_kernel(
        const float* __restrict__ fm, const float* __restrict__ ws,
        float* __restrict__ out) {
    __shared__ __align__(16) float smem[WS_FLOATS];   // 34.9 KB
    {
        const float4* src = (const float4*)ws;
        float4* dst = (float4*)smem;
        for (int i = threadIdx.x; i < WS_FLOATS / 4; i += 256) dst[i] = src[i];
    }
    __syncthreads();
    const unsigned short* sWf = (const unsigned short*)smem;
    const float* sUf = smem + WS_UF;
    const float* sHW = smem + WS_HW;

    const int lane = threadIdx.x & 63;
    const int c    = lane & 31;   // voxel within 32-group / D-tile column
    const int h    = lane >> 5;   // half-wave
    const int wid  = (blockIdx.x * 256 + (int)threadIdx.x) >> 6;  // 0..3071

    const float SCALE = -0.0036067376022224085f;  // -log2(e)/400

    // Hoist per-component uniforms into SGPRs (k-loop is fully unrolled, so
    // indices are static -> arrays stay scalar; removes 16 ds_read_b64/tile
    // from the dependent exp2 chain).
    float h2s[K_TOT], wks[K_TOT];
#pragma unroll
    for (int k2 = 0; k2 < K_TOT; ++k2) {
        h2s[k2] = rfl(sHW[k2 * 2]);
        wks[k2] = rfl(sHW[k2 * 2 + 1]);
    }

    float4 raw[16];               // next tile's raw f32 (in flight across k-half 2)
    short8 Blo[4], Bhi[4];        // current tile's B-fragments

    auto load_raw = [&](int tile) {
        size_t vb = (size_t)tile * 128;
#pragma unroll
        for (int g = 0; g < 4; ++g) {
            const float* xb = fm + (vb + g * 32 + c) * 32 + h * 8;
            raw[g * 4 + 0] = *(const float4*)(xb + 0);
            raw[g * 4 + 1] = *(const float4*)(xb + 4);
            raw[g * 4 + 2] = *(const float4*)(xb + 16);
            raw[g * 4 + 3] = *(const float4*)(xb + 20);
        }
    };
    auto cvt_all = [&]() {
#pragma unroll
        for (int g = 0; g < 4; ++g) {
            Blo[g] = cvt8(raw[g * 4 + 0], raw[g * 4 + 1]);
            Bhi[g] = cvt8(raw[g * 4 + 2], raw[g * 4 + 3]);
        }
    };

    // prologue: tile 0 of this wave
    load_raw(wid);
    cvt_all();

    float dens[4];
    auto kstep = [&](int kc) {
        const short8 Alo = *(const short8*)(sWf + ((size_t)(kc * 2 + 0) * 64 + lane) * 8);
        const short8 Ahi = *(const short8*)(sWf + ((size_t)(kc * 2 + 1) * 64 + lane) * 8);
        const f32x16 Cu  = *(const f32x16*)(sUf + kc * 32 + h * 16);
#pragma unroll
        for (int g = 0; g < 4; ++g) {
            f32x16 d = __builtin_amdgcn_mfma_f32_32x32x16_bf16(Alo, Blo[g], Cu, 0, 0, 0);
            d = __builtin_amdgcn_mfma_f32_32x32x16_bf16(Ahi, Bhi[g], d, 0, 0, 0);
            const f32x2* dp = (const f32x2*)&d;
            f32x2 acc0 = dp[0] * dp[0];
            f32x2 acc1 = dp[1] * dp[1];
#pragma unroll
            for (int r = 1; r < 4; ++r) {
                acc0 += dp[2 * r + 0] * dp[2 * r + 0];
                acc1 += dp[2 * r + 1] * dp[2 * r + 1];
            }
            f32x2 accs = acc0 + acc1;
            float p = accs[0] + accs[1];
            float pt = cross_half_sum(p);   // p + p[lane^32], VALU-only
            dens[g] = fmaf(wks[kc], __builtin_amdgcn_exp2f(fmaf(pt, SCALE, h2s[kc])), dens[g]);
        }
    };

#pragma unroll 1
    for (int it = 0; it < 3; ++it) {
        const int tile = wid + it * N_WAVES;
        dens[0] = dens[1] = dens[2] = dens[3] = 0.f;

#pragma unroll
        for (int kc = 0; kc < 8; ++kc) kstep(kc);

        if (it < 2) load_raw(wid + (it + 1) * N_WAVES);   // prefetch next tile

#pragma unroll
        for (int kc = 8; kc < 16; ++kc) kstep(kc);

        // Store: half-wave h writes groups {2h, 2h+1}; zero the z==63 slice
        // (z = (g*32 + c) & 63 == 63  <=>  c==31 && g odd).
        size_t vbase = (size_t)tile * 128;
#pragma unroll
        for (int gg = 0; gg < 2; ++gg) {
            int g = h * 2 + gg;
            float val = dens[g];
            if (c == 31 && (g & 1)) val = 0.f;
            out[vbase + g * 32 + c] = val;
        }

        if (it < 2) cvt_all();   // raw has landed under the k-loop
    }
}

extern "C" void kernel_launch(void* const* d_in, const int* in_sizes, int n_in,
                              void* d_out, int out_size, void* d_ws, size_t ws_size,
                              hipStream_t stream) {
    const float* fm = (const float*)d_in[0];
    const float* wb = (const float*)d_in[1];
    const float* mb = (const float*)d_in[2];
    const float* Lb = (const float*)d_in[3];
    const float* wf = (const float*)d_in[4];
    const float* mf = (const float*)d_in[5];
    const float* Lf = (const float*)d_in[6];
    float* out = (float*)d_out;
    float* ws  = (float*)d_ws;

    gmm_prep_kernel<<<K_TOT, 64, 0, stream>>>(wb, mb, Lb, wf, mf, Lf, ws);
    gmm_density_kernel<<<N_BLOCKS, 256, 0, stream>>>(fm, ws, out);
}

// Round 3
// 251.167 us; speedup vs baseline: 1.8924x; 1.8924x over previous
//
#include <hip/hip_runtime.h>
#include <hip/hip_bf16.h>
#include <cstring>

// Problem constants: B=2, X=96, Y=96, Z=64, C=32, K=16, LOG_PROB_SCALE=200
#define NVOX (2 * 96 * 96 * 64)
#define K_TOT 16
#define N_TILES (NVOX / 128)   // 9216 tiles of 128 voxels
#define N_WAVES 3072           // persistent: 768 blocks x 4 waves; 3 tiles/wave
#define N_BLOCKS 768

typedef __attribute__((ext_vector_type(8)))  short short8;   // 8 bf16 (A/B frag)
typedef __attribute__((ext_vector_type(16))) float f32x16;   // C/D frag
typedef __attribute__((ext_vector_type(2)))  float f32x2;
typedef __attribute__((ext_vector_type(2)))  unsigned int uint2v;

// ws layout:
//   bytes [0, 32768): A-frags bf16, ushort idx ((kc*2 + half)*64 + lane)*8 + j
//       = Linv[kc][m = lane&31][c = half*16 + (lane>>5)*8 + j]
//   floats [8192, 8704): uf[kc*32 + (lane>>5)*16 + reg] = -u_kc[(reg&3)+8*(reg>>2)+4*(lane>>5)]
//   floats [8704, 8736): pairs (h2[kc], w[kc]); h2 = log2e*(const - logdet)/200
#define WS_UF 8192
#define WS_HW 8704
#define WS_FLOATS 8736   // 34944 bytes

static __device__ __forceinline__ unsigned short f2b(float f) {
    __hip_bfloat16 h = __float2bfloat16(f);
    unsigned short u;
    __builtin_memcpy(&u, &h, 2);
    return u;
}

// Pack two f32 into a dword of two bf16 (round-half-up): 2x v_add_u32 + v_perm_b32.
static __device__ __forceinline__ int pack2_bf16(float f0, float f1) {
    unsigned a, b;
    __builtin_memcpy(&a, &f0, 4);
    __builtin_memcpy(&b, &f1, 4);
    return (int)__builtin_amdgcn_perm(b + 0x8000u, a + 0x8000u, 0x07060302u);
}

static __device__ __forceinline__ short8 cvt8(float4 lo, float4 hi) {
    int p0 = pack2_bf16(lo.x, lo.y);
    int p1 = pack2_bf16(lo.z, lo.w);
    int p2 = pack2_bf16(hi.x, hi.y);
    int p3 = pack2_bf16(hi.z, hi.w);
    int v[4] = {p0, p1, p2, p3};
    short8 r;
    __builtin_memcpy(&r, v, 16);
    return r;
}

// readfirstlane for float (value is wave-uniform; pins it into an SGPR)
static __device__ __forceinline__ float rfl(float x) {
    int i;
    __builtin_memcpy(&i, &x, 4);
    i = __builtin_amdgcn_readfirstlane(i);
    float r;
    __builtin_memcpy(&r, &i, 4);
    return r;
}

// Sum p across the two 32-lane halves: returns p[lane] + p[lane^32] in every
// lane. permlane32_swap builtin (VALU-only; verified correct+passing in r2).
static __device__ __forceinline__ float cross_half_sum(float p) {
#if __has_builtin(__builtin_amdgcn_permlane32_swap)
    unsigned pu;
    __builtin_memcpy(&pu, &p, 4);
    uint2v r = __builtin_amdgcn_permlane32_swap(pu, pu, false, false);
    unsigned a = r.x, b = r.y;
    float fa, fb;
    __builtin_memcpy(&fa, &a, 4);
    __builtin_memcpy(&fb, &b, 4);
    return fa + fb;   // {lo,lo} + {hi,hi} in each lane = p + p[lane^32]
#else
    return p + __shfl_xor(p, 32);
#endif
}

__global__ void gmm_prep_kernel(const float* __restrict__ wb, const float* __restrict__ mb,
                                const float* __restrict__ Lb, const float* __restrict__ wf,
                                const float* __restrict__ mf, const float* __restrict__ Lf,
                                float* __restrict__ ws) {
    int k   = blockIdx.x;   // component
    int tid = threadIdx.x;  // 64 threads

    __shared__ float Lsh[1024];   // L_k row-major
    __shared__ float Lish[1024];  // Linv_k row-major (upper tri = 0)
    __shared__ float ush[32];     // u = Linv * mu

    const float* L  = (k < 8) ? (Lb + k * 1024) : (Lf + (k - 8) * 1024);
    const float* mu = (k < 8) ? (mb + k * 32)   : (mf + (k - 8) * 32);

    for (int i = tid; i < 1024; i += 64) Lsh[i] = L[i];
    __syncthreads();

    if (tid < 32) {
        int j = tid;  // solve column j: L * col = e_j
        float col[32];
#pragma unroll
        for (int i = 0; i < 32; ++i) {
            float s = (i == j) ? 1.0f : 0.0f;
#pragma unroll
            for (int m = 0; m < i; ++m) s = fmaf(-Lsh[i * 32 + m], col[m], s);
            float val = s / Lsh[i * 32 + i];
            col[i] = (i >= j) ? val : 0.0f;
        }
#pragma unroll
        for (int i = 0; i < 32; ++i) Lish[i * 32 + j] = col[i];
    }
    __syncthreads();
    if (tid < 32) {
        int d = tid;
        float s = 0.0f;
        for (int c = 0; c <= d; ++c) s = fmaf(Lish[d * 32 + c], mu[c], s);
        ush[d] = s;
    }
    __syncthreads();

    // A-fragments in MFMA 32x32x16 operand order, bf16 (RNE; prep is cold).
    unsigned short* wsA = (unsigned short*)ws;
    int m  = tid & 31;   // outdim row
    int kq = tid >> 5;   // k-half-of-8 within the MFMA's K=16
#pragma unroll
    for (int hf = 0; hf < 2; ++hf) {  // channel halves 0..15 / 16..31
        unsigned short* dst = wsA + (size_t)(((k * 2 + hf) * 64 + tid) * 8);
#pragma unroll
        for (int j = 0; j < 8; ++j)
            dst[j] = f2b(Lish[m * 32 + hf * 16 + kq * 8 + j]);
    }
    // -u in C/D fragment order
    if (tid < 32) {
        int h = tid >> 4, r = tid & 15;
        ws[WS_UF + k * 32 + tid] = -ush[(r & 3) + 8 * (r >> 2) + 4 * h];
    }
    if (tid == 0) {
        float ld = 0.0f;
        for (int i = 0; i < 32; ++i) ld += logf(Lsh[i * 32 + i]);
        const float cconst = -0.5f * 32.0f * 1.8378770664093453f;  // -C/2*log(2pi)
        const float log2e  = 1.4426950408889634f;
        ws[WS_HW + k * 2]     = (cconst - ld) * (1.0f / 200.0f) * log2e;
        ws[WS_HW + k * 2 + 1] = (k < 8) ? wb[k] : wf[k - 8];
    }
}

// Persistent kernel: 768 blocks x 4 waves = 3072 waves, 3 tiles per wave.
// Cross-tile software pipeline with TWO 8-load prefetch batches (32 raw VGPRs
// in flight max — round-1's single 16-load batch kept 64 raw VGPRs live at
// the drain point, total demand ~170 > the (256,3) 168-reg cap -> wholesale
// scratch spill, WRITE_SIZE 427 MB, 316 us). Schedule per tile t (it<2):
//   kc 0..7   compute   | after kc=7:  issue batch A (g0,g1 of t+1) -> ra
//   kc 8..11  compute   | after kc=11: cvt A -> Bn (ra dies), issue batch B -> rb
//   kc 12..15 compute + store | then: Blo[0..1]=Bn, cvt B -> Blo[2..3]
// Each batch gets ~4 ksteps (~600-800 cyc) of MFMA/VALU cover for HBM latency.
// 3-tile loop fully unrolled: every array index compile-time constant.
__global__ __launch_bounds__(256, 3) void gmm_density_kernel(
        const float* __restrict__ fm, const float* __restrict__ ws,
        float* __restrict__ out) {
    __shared__ __align__(16) float smem[WS_FLOATS];   // 34.9 KB
    {
        const float4* src = (const float4*)ws;
        float4* dst = (float4*)smem;
        for (int i = threadIdx.x; i < WS_FLOATS / 4; i += 256) dst[i] = src[i];
    }
    __syncthreads();
    const unsigned short* sWf = (const unsigned short*)smem;
    const float* sUf = smem + WS_UF;
    const float* sHW = smem + WS_HW;

    const int lane = threadIdx.x & 63;
    const int c    = lane & 31;   // voxel within 32-group / D-tile column
    const int h    = lane >> 5;   // half-wave
    const int wid  = (blockIdx.x * 256 + (int)threadIdx.x) >> 6;  // 0..3071

    const float SCALE = -0.0036067376022224085f;  // -log2(e)/400

    // Per-component uniforms in SGPRs (static indices after unroll).
    float h2s[K_TOT], wks[K_TOT];
#pragma unroll
    for (int k2 = 0; k2 < K_TOT; ++k2) {
        h2s[k2] = rfl(sHW[k2 * 2]);
        wks[k2] = rfl(sHW[k2 * 2 + 1]);
    }

    short8 Blo[4], Bhi[4];        // current tile's B-fragments
    short8 BnLo[2], BnHi[2];      // next tile's g0,g1 staging
    float4 ra[8], rb[8];          // in-flight raw f32, 8 loads per batch
    float dens[4];

    auto load8 = [&](float4* r, int tile, int gbase) {
        size_t vb = (size_t)tile * 128;
#pragma unroll
        for (int gg = 0; gg < 2; ++gg) {
            const float* xb = fm + (vb + (gbase + gg) * 32 + c) * 32 + h * 8;
            r[gg * 4 + 0] = *(const float4*)(xb + 0);
            r[gg * 4 + 1] = *(const float4*)(xb + 4);
            r[gg * 4 + 2] = *(const float4*)(xb + 16);
            r[gg * 4 + 3] = *(const float4*)(xb + 20);
        }
    };

    auto kstep = [&](int kc) {
        const short8 Alo = *(const short8*)(sWf + ((size_t)(kc * 2 + 0) * 64 + lane) * 8);
        const short8 Ahi = *(const short8*)(sWf + ((size_t)(kc * 2 + 1) * 64 + lane) * 8);
        const f32x16 Cu  = *(const f32x16*)(sUf + kc * 32 + h * 16);
#pragma unroll
        for (int g = 0; g < 4; ++g) {
            f32x16 d = __builtin_amdgcn_mfma_f32_32x32x16_bf16(Alo, Blo[g], Cu, 0, 0, 0);
            d = __builtin_amdgcn_mfma_f32_32x32x16_bf16(Ahi, Bhi[g], d, 0, 0, 0);
            const f32x2* dp = (const f32x2*)&d;
            f32x2 acc0 = dp[0] * dp[0];
            f32x2 acc1 = dp[1] * dp[1];
#pragma unroll
            for (int r = 1; r < 4; ++r) {
                acc0 += dp[2 * r + 0] * dp[2 * r + 0];
                acc1 += dp[2 * r + 1] * dp[2 * r + 1];
            }
            f32x2 accs = acc0 + acc1;
            float p = accs[0] + accs[1];
            float pt = cross_half_sum(p);   // p + p[lane^32], VALU-only
            dens[g] = fmaf(wks[kc], __builtin_amdgcn_exp2f(fmaf(pt, SCALE, h2s[kc])), dens[g]);
        }
    };

    // prologue: tile `wid` (both batches, no overlap available yet)
    load8(ra, wid, 0);
    load8(rb, wid, 2);
    Blo[0] = cvt8(ra[0], ra[1]); Bhi[0] = cvt8(ra[2], ra[3]);
    Blo[1] = cvt8(ra[4], ra[5]); Bhi[1] = cvt8(ra[6], ra[7]);
    Blo[2] = cvt8(rb[0], rb[1]); Bhi[2] = cvt8(rb[2], rb[3]);
    Blo[3] = cvt8(rb[4], rb[5]); Bhi[3] = cvt8(rb[6], rb[7]);

#pragma unroll
    for (int it = 0; it < 3; ++it) {
        const int tile = wid + it * N_WAVES;
        dens[0] = dens[1] = dens[2] = dens[3] = 0.f;

#pragma unroll
        for (int kc = 0; kc < 8; ++kc) kstep(kc);

        if (it < 2) load8(ra, tile + N_WAVES, 0);   // batch A for tile t+1

#pragma unroll
        for (int kc = 8; kc < 12; ++kc) kstep(kc);

        if (it < 2) {
            // batch A has had ~4 ksteps of cover: convert, free ra, issue batch B
            BnLo[0] = cvt8(ra[0], ra[1]); BnHi[0] = cvt8(ra[2], ra[3]);
            BnLo[1] = cvt8(ra[4], ra[5]); BnHi[1] = cvt8(ra[6], ra[7]);
            load8(rb, tile + N_WAVES, 2);           // batch B for tile t+1
        }

#pragma unroll
        for (int kc = 12; kc < 16; ++kc) kstep(kc);

        // Store: half-wave h writes groups {2h, 2h+1}; zero the z==63 slice
        // (z = (g*32 + c) & 63 == 63  <=>  c==31 && g odd).
        size_t vbase = (size_t)tile * 128;
#pragma unroll
        for (int gg = 0; gg < 2; ++gg) {
            int g = h * 2 + gg;
            float val = dens[g];
            if (c == 31 && (g & 1)) val = 0.f;
            out[vbase + g * 32 + c] = val;
        }

        if (it < 2) {
            Blo[0] = BnLo[0]; Bhi[0] = BnHi[0];
            Blo[1] = BnLo[1]; Bhi[1] = BnHi[1];
            Blo[2] = cvt8(rb[0], rb[1]); Bhi[2] = cvt8(rb[2], rb[3]);
            Blo[3] = cvt8(rb[4], rb[5]); Bhi[3] = cvt8(rb[6], rb[7]);
        }
    }
}

extern "C" void kernel_launch(void* const* d_in, const int* in_sizes, int n_in,
                              void* d_out, int out_size, void* d_ws, size_t ws_size,
                              hipStream_t stream) {
    const float* fm = (const float*)d_in[0];
    const float* wb = (const float*)d_in[1];
    const float* mb = (const float*)d_in[2];
    const float* Lb = (const float*)d_in[3];
    const float* wf = (const float*)d_in[4];
    const float* mf = (const float*)d_in[5];
    const float* Lf = (const float*)d_in[6];
    float* out = (float*)d_out;
    float* ws  = (float*)d_ws;

    gmm_prep_kernel<<<K_TOT, 64, 0, stream>>>(wb, mb, Lb, wf, mf, Lf, ws);
    gmm_density_kernel<<<N_BLOCKS, 256, 0, stream>>>(fm, ws, out);
}